// Round 7
// baseline (417.543 us; speedup 1.0000x reference)
//
#include <hip/hip_runtime.h>
#include <hip/hip_bf16.h>

// ---------------------------------------------------------------------------
// Problem: N=2, S=2048, C=1024, A=1024, H=16, d=64, MAXLEN=2048
// Outputs: y [2,2048,1024] fp32  then  attn [2,16,2048,2048] fp32 (concat flat)
// ---------------------------------------------------------------------------

typedef __attribute__((ext_vector_type(8))) short s16x8;   // 8 x bf16 bits (4 VGPR)
typedef __attribute__((ext_vector_type(4))) float f32x4;   // MFMA acc

#define NEGV (-1e30f)
#define K1   0.1803368801111244f   /* 0.125 * log2(e) */

static __device__ __forceinline__ short f2bf(float f) {
  unsigned u = __float_as_uint(f);
  unsigned r = (u + 0x7fffu + ((u >> 16) & 1u)) >> 16;
  return (short)r;
}
static __device__ __forceinline__ float bf2f(short s) {
  return __uint_as_float(((unsigned)(unsigned short)s) << 16);
}

// async global->LDS, 16B per lane; lds dest wave-uniform (HW adds lane*16)
static __device__ __forceinline__ void gload_lds16(const void* g, void* l) {
  __builtin_amdgcn_global_load_lds(
      (const __attribute__((address_space(1))) void*)g,
      (__attribute__((address_space(3))) void*)l, 16, 0, 0);
}

// ---------------- elementwise cast fp32 -> bf16 ----------------------------
__global__ void cast_f32_bf16(const float* __restrict__ in, short* __restrict__ out, int n) {
  int i = (blockIdx.x * 256 + threadIdx.x) * 8;
  if (i >= n) return;
  float4 a = *(const float4*)&in[i];
  float4 b = *(const float4*)&in[i + 4];
  s16x8 v;
  v[0] = f2bf(a.x); v[1] = f2bf(a.y); v[2] = f2bf(a.z); v[3] = f2bf(a.w);
  v[4] = f2bf(b.x); v[5] = f2bf(b.y); v[6] = f2bf(b.z); v[7] = f2bf(b.w);
  *(s16x8*)&out[i] = v;
}

// ---------------- transpose + cast: [R][Cc] fp32 -> [Cc][R] bf16 -----------
__global__ void transpose_cast(const float* __restrict__ in, short* __restrict__ out,
                               int R, int Cc) {
  __shared__ float tile[32][33];
  int c0 = blockIdx.x * 32, r0 = blockIdx.y * 32;
  int tx = threadIdx.x, ty = threadIdx.y;          // block (32,8)
  for (int i = 0; i < 32; i += 8)
    tile[ty + i][tx] = in[(size_t)(r0 + ty + i) * Cc + c0 + tx];
  __syncthreads();
  for (int i = 0; i < 32; i += 8)
    out[(size_t)(c0 + ty + i) * R + r0 + tx] = f2bf(tile[tx][ty + i]);
}

// -------- rel_table [2048][16] fp32 -> [16][2048] bf16, scaled by log2e ----
__global__ void transpose_table_k(const float* __restrict__ in, short* __restrict__ out) {
  int i = blockIdx.x * 256 + threadIdx.x;
  if (i >= 2048 * 16) return;
  int l = i >> 4, h = i & 15;
  out[h * 2048 + l] = f2bf(in[i] * 1.4426950408889634f);
}

// ---------------- mask [2][2048] int -> 64 u64 bitwords --------------------
__global__ void mask_pack(const int* __restrict__ mask, unsigned long long* __restrict__ mkb) {
  int g = blockIdx.x * 256 + threadIdx.x;          // 0..4095
  unsigned long long b = __ballot(mask[g] != 0);
  if ((threadIdx.x & 63) == 0) mkb[g >> 6] = b;
}

// ---------------- V pre-transpose: qkv V-part -> VT[n][vcol][s] bf16 -------
__global__ void vt_transpose(const short* __restrict__ qkv, short* __restrict__ vt) {
  __shared__ short tile[32][33];
  int nn = blockIdx.z;
  int c0 = blockIdx.y * 32;                        // v-col (= h*64+dd)
  int r0 = blockIdx.x * 32;                        // s
  int tx = threadIdx.x, ty = threadIdx.y;          // block (32,8)
  for (int i = 0; i < 32; i += 8)
    tile[ty + i][tx] = qkv[(size_t)(nn * 2048 + r0 + ty + i) * 3072 + 2048 + c0 + tx];
  __syncthreads();
  for (int i = 0; i < 32; i += 8)
    vt[(size_t)(nn * 1024 + c0 + ty + i) * 2048 + r0 + tx] = tile[tx][ty + i];
}

// ---------------- bf16 MFMA GEMM (m97 structure): C = A * BT^T -------------
template<bool OUT_F32>
__global__ __launch_bounds__(256) void gemm_bt(
    const short* __restrict__ A, const short* __restrict__ BT,
    void* __restrict__ Cout, int M, int Nn, int K)
{
  __shared__ short As[128 * 64];
  __shared__ short Bs[128 * 64];
  int bn = blockIdx.x, bm = blockIdx.y;
  int tid = threadIdx.x, wave = tid >> 6, lane = tid & 63;
  int wr = wave >> 1, wc = wave & 1;
  int lc = lane & 15, lg = lane >> 4;
  f32x4 acc[4][4];
  for (int i = 0; i < 4; ++i)
    for (int j = 0; j < 4; ++j) acc[i][j] = (f32x4){0.f, 0.f, 0.f, 0.f};
  const short* Abase = A  + (size_t)(bm * 128) * K;
  const short* Bbase = BT + (size_t)(bn * 128) * K;
  int srow = lane >> 3;
  int scol = (lane & 7) * 8;
  for (int k0 = 0; k0 < K; k0 += 64) {
    __syncthreads();
    #pragma unroll
    for (int it = 0; it < 4; ++it) {
      int chunk = it * 4 + wave;
      int grow = chunk * 8 + srow;
      gload_lds16(&Abase[(size_t)grow * K + k0 + scol], &As[chunk * 512]);
      gload_lds16(&Bbase[(size_t)grow * K + k0 + scol], &Bs[chunk * 512]);
    }
    __syncthreads();
    #pragma unroll
    for (int ks = 0; ks < 2; ++ks) {
      s16x8 af[4], bfr[4];
      #pragma unroll
      for (int mi = 0; mi < 4; ++mi)
        af[mi] = *(const s16x8*)&As[(wr * 64 + mi * 16 + lc) * 64 + ks * 32 + lg * 8];
      #pragma unroll
      for (int ni = 0; ni < 4; ++ni)
        bfr[ni] = *(const s16x8*)&Bs[(wc * 64 + ni * 16 + lc) * 64 + ks * 32 + lg * 8];
      #pragma unroll
      for (int mi = 0; mi < 4; ++mi)
        #pragma unroll
        for (int ni = 0; ni < 4; ++ni)
          acc[mi][ni] = __builtin_amdgcn_mfma_f32_16x16x32_bf16(af[mi], bfr[ni], acc[mi][ni], 0, 0, 0);
    }
  }
  int row0 = bm * 128 + wr * 64, col0 = bn * 128 + wc * 64;
  for (int mi = 0; mi < 4; ++mi)
    for (int ni = 0; ni < 4; ++ni)
      for (int r = 0; r < 4; ++r) {
        int row = row0 + mi * 16 + lg * 4 + r;
        int col = col0 + ni * 16 + lc;
        if constexpr (OUT_F32)
          ((float*)Cout)[(size_t)row * Nn + col] = acc[mi][ni][r];
        else
          ((short*)Cout)[(size_t)row * Nn + col] = f2bf(acc[mi][ni][r]);
      }
}

// ---------------- GEMM variant: 128x64 tile (for y = y_ws @ WoutT) ---------
__global__ __launch_bounds__(256) void gemm_bt64(
    const short* __restrict__ A, const short* __restrict__ BT,
    float* __restrict__ Cout, int M, int Nn, int K)
{
  __shared__ short As[128 * 64];
  __shared__ short Bs[64 * 64];
  int bn = blockIdx.x, bm = blockIdx.y;
  int tid = threadIdx.x, wave = tid >> 6, lane = tid & 63;
  int wr = wave >> 1, wc = wave & 1;
  int lc = lane & 15, lg = lane >> 4;
  f32x4 acc[4][2];
  for (int i = 0; i < 4; ++i)
    for (int j = 0; j < 2; ++j) acc[i][j] = (f32x4){0.f, 0.f, 0.f, 0.f};
  const short* Abase = A  + (size_t)(bm * 128) * K;
  const short* Bbase = BT + (size_t)(bn * 64) * K;
  int srow = lane >> 3;
  int scol = (lane & 7) * 8;
  for (int k0 = 0; k0 < K; k0 += 64) {
    __syncthreads();
    #pragma unroll
    for (int it = 0; it < 4; ++it) {
      int chunk = it * 4 + wave;
      gload_lds16(&Abase[(size_t)(chunk * 8 + srow) * K + k0 + scol], &As[chunk * 512]);
    }
    #pragma unroll
    for (int it = 0; it < 2; ++it) {
      int chunk = it * 4 + wave;
      gload_lds16(&Bbase[(size_t)(chunk * 8 + srow) * K + k0 + scol], &Bs[chunk * 512]);
    }
    __syncthreads();
    #pragma unroll
    for (int ks = 0; ks < 2; ++ks) {
      s16x8 af[4], bfr[2];
      #pragma unroll
      for (int mi = 0; mi < 4; ++mi)
        af[mi] = *(const s16x8*)&As[(wr * 64 + mi * 16 + lc) * 64 + ks * 32 + lg * 8];
      #pragma unroll
      for (int ni = 0; ni < 2; ++ni)
        bfr[ni] = *(const s16x8*)&Bs[(wc * 32 + ni * 16 + lc) * 64 + ks * 32 + lg * 8];
      #pragma unroll
      for (int mi = 0; mi < 4; ++mi)
        #pragma unroll
        for (int ni = 0; ni < 2; ++ni)
          acc[mi][ni] = __builtin_amdgcn_mfma_f32_16x16x32_bf16(af[mi], bfr[ni], acc[mi][ni], 0, 0, 0);
    }
  }
  int row0 = bm * 128 + wr * 64, col0 = bn * 64 + wc * 32;
  for (int mi = 0; mi < 4; ++mi)
    for (int ni = 0; ni < 2; ++ni)
      for (int r = 0; r < 4; ++r)
        Cout[(size_t)(row0 + mi * 16 + lg * 4 + r) * Nn + col0 + ni * 16 + lc] = acc[mi][ni][r];
}

// ---------------- fused attention: barrier-free, one wave per 16-row strip -
// grid 4096 x 64 threads. bid -> xcd=bid&7 (nh%8 = XCD affinity), strip desc
// (LPT). Each wave independent; K/V straight from global (L2-resident per
// XCD); P via wave-local LDS strip. No in-loop barriers -> stores stream.
// R7 fixes vs R6: c[] zero-init (was UB when guard-skipped); Ps accessed as
// uint2 on BOTH sides + asm memory fence between P-write and PV-read (TBAA
// could legally reorder the ds_read above the ds_write with mixed types).
__global__ __launch_bounds__(64, 4) void attn_fused(
    const short* __restrict__ qkv,     // [4096][3072] bf16
    const short* __restrict__ vt,      // [2][1024][2048] bf16 (V^T)
    const unsigned long long* __restrict__ mkb,  // [2][32]
    const short* __restrict__ tabS,    // [16][2048] bf16, *log2e
    float* __restrict__ attn_out,      // [2][16][2048][2048]
    short* __restrict__ y_ws)          // [4096][1024] bf16
{
  int bid = blockIdx.x;
  int xcd = bid & 7, rr_ = bid >> 3;
  int strip = 127 - (rr_ & 127);       // 16-row q-strip, desc (LPT)
  int nh = xcd + 8 * (rr_ >> 7);
  int n = nh >> 4, h = nh & 15;
  int lane = threadIdx.x;
  int lc = lane & 15, lg = lane >> 4, lg4 = lg * 4;

  __shared__ short btab[2048];
  __shared__ short Ps[16][72];         // wave-local P strip (uint2 access both sides)

  #pragma unroll
  for (int i = 0; i < 4; ++i)
    *(s16x8*)&btab[(i * 64 + lane) * 8] = *(const s16x8*)&tabS[h * 2048 + (i * 64 + lane) * 8];
  __syncthreads();                     // single wave: cheap; full fence for btab

  int q0 = strip * 16;
  int qrow = q0 + lc;
  const unsigned long long* mw = mkb + n * 32;
  bool qv = ((mw[qrow >> 6] >> (qrow & 63)) & 1ull) != 0;
  int NT = (strip >> 2) + 1;           // causal k-tiles for this strip

  const short* qb = qkv + (size_t)(n * 2048 + qrow) * 3072 + h * 64;
  const short* kl = qkv + (size_t)(n * 2048) * 3072 + 1024 + h * 64;
  const short* vl = vt + (size_t)(n * 1024 + h * 64) * 2048;
  float* aout = attn_out + (size_t)(n * 16 + h) * 2048 * 2048;

  s16x8 aq[2];
  aq[0] = *(const s16x8*)&qb[lg * 8];
  aq[1] = *(const s16x8*)&qb[32 + lg * 8];

  // ---------------- sweep 1: row sums (max-free, no stores) ----------------
  float l = 0.f;
  for (int kt = 0; kt < NT; ++kt) {
    const short* kp = kl + (size_t)(kt * 64 + lc) * 3072 + lg * 8;
    unsigned long long w = mw[kt];
    int lim = qrow - kt * 64;
    f32x4 c[4];
    #pragma unroll
    for (int ni = 0; ni < 4; ++ni) c[ni] = (f32x4){0.f, 0.f, 0.f, 0.f};
    #pragma unroll
    for (int ni = 0; ni < 4; ++ni) {
      if (kt * 64 + ni * 16 <= q0 + 15) {        // uniform: subtile touches diag
        s16x8 k0 = *(const s16x8*)&kp[(size_t)(ni * 16) * 3072];
        s16x8 k1 = *(const s16x8*)&kp[(size_t)(ni * 16) * 3072 + 32];
        __builtin_amdgcn_s_setprio(1);
        c[ni] = __builtin_amdgcn_mfma_f32_16x16x32_bf16(k0, aq[0], c[ni], 0, 0, 0);
        c[ni] = __builtin_amdgcn_mfma_f32_16x16x32_bf16(k1, aq[1], c[ni], 0, 0, 0);
        __builtin_amdgcn_s_setprio(0);
        #pragma unroll
        for (int r = 0; r < 4; ++r) {
          int idx = ni * 16 + lg4 + r;
          bool ok = (((w >> idx) & 1ull) != 0) && (idx <= lim);
          float bb = bf2f(btab[lim - idx]);      // OOB-masked garbage ok
          float v = ok ? fmaf(c[ni][r], K1, bb) : NEGV;
          l += exp2f(v);
        }
      }
    }
  }
  l += __shfl_xor(l, 16);
  l += __shfl_xor(l, 32);
  float C_ = __log2f(l);               // p = exp2(val - C_); qv rows have l>0

  f32x4 y[4];
  #pragma unroll
  for (int ni = 0; ni < 4; ++ni) y[ni] = (f32x4){0.f, 0.f, 0.f, 0.f};

  // ---------------- sweep 2: normalized attn (float4) + PV -----------------
  for (int kt = 0; kt < NT; ++kt) {
    const short* kp = kl + (size_t)(kt * 64 + lc) * 3072 + lg * 8;
    const short* vp = vl + (size_t)lc * 2048 + kt * 64 + lg * 8;
    unsigned long long w = mw[kt];
    int lim = qrow - kt * 64;

    // QK^T (guarded per ni-subtile; c zero-init so skipped tiles are defined)
    f32x4 c[4];
    #pragma unroll
    for (int ni = 0; ni < 4; ++ni) c[ni] = (f32x4){0.f, 0.f, 0.f, 0.f};
    #pragma unroll
    for (int ni = 0; ni < 4; ++ni) {
      if (kt * 64 + ni * 16 <= q0 + 15) {
        s16x8 k0 = *(const s16x8*)&kp[(size_t)(ni * 16) * 3072];
        s16x8 k1 = *(const s16x8*)&kp[(size_t)(ni * 16) * 3072 + 32];
        __builtin_amdgcn_s_setprio(1);
        c[ni] = __builtin_amdgcn_mfma_f32_16x16x32_bf16(k0, aq[0], c[ni], 0, 0, 0);
        c[ni] = __builtin_amdgcn_mfma_f32_16x16x32_bf16(k1, aq[1], c[ni], 0, 0, 0);
        __builtin_amdgcn_s_setprio(0);
      }
    }

    // V frags (issue early; consumed after emit)
    s16x8 vf[4][2];
    #pragma unroll
    for (int ni = 0; ni < 4; ++ni) {
      vf[ni][0] = *(const s16x8*)&vp[(size_t)(ni * 16) * 2048];
      vf[ni][1] = *(const s16x8*)&vp[(size_t)(ni * 16) * 2048 + 32];
    }

    // emit: p = exp2(val - C_), store float4, pack bf16 into wave-local Ps
    #pragma unroll
    for (int ni = 0; ni < 4; ++ni) {
      float4 p4;
      #pragma unroll
      for (int r = 0; r < 4; ++r) {
        int idx = ni * 16 + lg4 + r;
        bool ok = (((w >> idx) & 1ull) != 0) && (idx <= lim) && qv;
        float bb = bf2f(btab[lim - idx]);
        float v = ok ? (fmaf(c[ni][r], K1, bb) - C_) : -3.0e38f;
        (&p4.x)[r] = exp2f(v);
      }
      *(float4*)&aout[(size_t)qrow * 2048 + kt * 64 + ni * 16 + lg4] = p4;
      unsigned plo = (unsigned)(unsigned short)f2bf(p4.x) | ((unsigned)(unsigned short)f2bf(p4.y) << 16);
      unsigned phi = (unsigned)(unsigned short)f2bf(p4.z) | ((unsigned)(unsigned short)f2bf(p4.w) << 16);
      uint2 pk; pk.x = plo; pk.y = phi;
      *(uint2*)&Ps[lc][ni * 16 + lg4] = pk;      // wave-local: no barrier needed
    }

    // fence: forbid hoisting the Ps reads above the Ps writes
    asm volatile("" ::: "memory");

    // PV (Ps read as uint2 = same access type as the writes)
    __builtin_amdgcn_s_setprio(1);
    #pragma unroll
    for (int ks = 0; ks < 2; ++ks) {
      union { uint2 u2[2]; s16x8 v; } pw;
      pw.u2[0] = *(const uint2*)&Ps[lc][ks * 32 + lg * 8];
      pw.u2[1] = *(const uint2*)&Ps[lc][ks * 32 + lg * 8 + 4];
      s16x8 pa = pw.v;
      #pragma unroll
      for (int ni = 0; ni < 4; ++ni)
        y[ni] = __builtin_amdgcn_mfma_f32_16x16x32_bf16(pa, vf[ni][ks], y[ni], 0, 0, 0);
    }
    __builtin_amdgcn_s_setprio(0);
  }

  // zero upper triangle of this strip (each attn byte written exactly once)
  {
    float4 z4 = {0.f, 0.f, 0.f, 0.f};
    float* dst = aout + (size_t)qrow * 2048;
    for (int cc = NT * 64 + lg4; cc < 2048; cc += 16)
      *(float4*)&dst[cc] = z4;
  }

  // y store (padded-query rows: all p forced 0 -> y 0)
  #pragma unroll
  for (int ni = 0; ni < 4; ++ni)
    #pragma unroll
    for (int r = 0; r < 4; ++r)
      y_ws[(size_t)(n * 2048 + q0 + lg4 + r) * 1024 + h * 64 + ni * 16 + lc] = f2bf(y[ni][r]);
}

// ---------------------------------------------------------------------------
extern "C" void kernel_launch(void* const* d_in, const int* in_sizes, int n_in,
                              void* d_out, int out_size, void* d_ws, size_t ws_size,
                              hipStream_t stream)
{
  const float* x         = (const float*)d_in[0];
  const int*   mask      = (const int*)d_in[1];
  const float* W_qkv     = (const float*)d_in[4];
  const float* W_out     = (const float*)d_in[5];
  const float* rel_table = (const float*)d_in[6];

  char* ws = (char*)d_ws;
  short*  xb     = (short*)(ws);                 //  8,388,608 B (reused as vt)
  short*  WqkvT  = (short*)(ws + 8388608);       //  6,291,456 B
  short*  WoutT  = (short*)(ws + 14680064);      //  2,097,152 B
  short*  tabS   = (short*)(ws + 16777216);      //     65,536 B
  unsigned long long* mkb = (unsigned long long*)(ws + 16842752); // 512 B
  short*  qkv    = (short*)(ws + 16908288);      // 25,165,824 B
  short*  y_ws   = (short*)(ws + 42074112);      //  8,388,608 B
  short*  vt     = xb;                           // V^T, written after gemm1 reads xb

  float* y_out    = (float*)d_out;
  float* attn_out = y_out + (size_t)2 * 2048 * 1024;

  cast_f32_bf16<<<2048, 256, 0, stream>>>(x, xb, 4194304);
  transpose_cast<<<dim3(3072 / 32, 1024 / 32), dim3(32, 8), 0, stream>>>(W_qkv, WqkvT, 1024, 3072);
  transpose_cast<<<dim3(1024 / 32, 1024 / 32), dim3(32, 8), 0, stream>>>(W_out, WoutT, 1024, 1024);
  transpose_table_k<<<128, 256, 0, stream>>>(rel_table, tabS);
  mask_pack<<<16, 256, 0, stream>>>(mask, mkb);

  gemm_bt<false><<<dim3(24, 32), 256, 0, stream>>>(xb, WqkvT, (void*)qkv, 4096, 3072, 1024);

  vt_transpose<<<dim3(64, 32, 2), dim3(32, 8), 0, stream>>>(qkv, vt);

  attn_fused<<<4096, 64, 0, stream>>>(qkv, vt, mkb, tabS, attn_out, y_ws);

  gemm_bt64<<<dim3(16, 32), 256, 0, stream>>>(y_ws, WoutT, y_out, 4096, 1024, 1024);
}

// Round 8
// 295.217 us; speedup vs baseline: 1.4144x; 1.4144x over previous
//
#include <hip/hip_runtime.h>
#include <hip/hip_bf16.h>

// ---------------------------------------------------------------------------
// Problem: N=2, S=2048, C=1024, A=1024, H=16, d=64, MAXLEN=2048
// Outputs: y [2,2048,1024] fp32  then  attn [2,16,2048,2048] fp32 (concat flat)
// ---------------------------------------------------------------------------

typedef __attribute__((ext_vector_type(8))) short s16x8;   // 8 x bf16 bits (4 VGPR)
typedef __attribute__((ext_vector_type(4))) float f32x4;   // MFMA acc

#define NEGV (-1e30f)
#define K1   0.1803368801111244f   /* 0.125 * log2(e) */

static __device__ __forceinline__ short f2bf(float f) {
  unsigned u = __float_as_uint(f);
  unsigned r = (u + 0x7fffu + ((u >> 16) & 1u)) >> 16;
  return (short)r;
}
static __device__ __forceinline__ float bf2f(short s) {
  return __uint_as_float(((unsigned)(unsigned short)s) << 16);
}

// async global->LDS, 16B per lane; lds dest wave-uniform (HW adds lane*16)
static __device__ __forceinline__ void gload_lds16(const void* g, void* l) {
  __builtin_amdgcn_global_load_lds(
      (const __attribute__((address_space(1))) void*)g,
      (__attribute__((address_space(3))) void*)l, 16, 0, 0);
}

// barrier that does NOT drain vmcnt: attn global stores stay in flight.
// staging is reg->ds_write, so lgkmcnt(0) suffices for LDS visibility.
static __device__ __forceinline__ void block_sync_lds() {
  __builtin_amdgcn_sched_barrier(0);
  asm volatile("s_waitcnt lgkmcnt(0)" ::: "memory");
  __builtin_amdgcn_s_barrier();
  __builtin_amdgcn_sched_barrier(0);
}

// ---------------- elementwise cast fp32 -> bf16 ----------------------------
__global__ void cast_f32_bf16(const float* __restrict__ in, short* __restrict__ out, int n) {
  int i = (blockIdx.x * 256 + threadIdx.x) * 8;
  if (i >= n) return;
  float4 a = *(const float4*)&in[i];
  float4 b = *(const float4*)&in[i + 4];
  s16x8 v;
  v[0] = f2bf(a.x); v[1] = f2bf(a.y); v[2] = f2bf(a.z); v[3] = f2bf(a.w);
  v[4] = f2bf(b.x); v[5] = f2bf(b.y); v[6] = f2bf(b.z); v[7] = f2bf(b.w);
  *(s16x8*)&out[i] = v;
}

// ---------------- transpose + cast: [R][Cc] fp32 -> [Cc][R] bf16 -----------
__global__ void transpose_cast(const float* __restrict__ in, short* __restrict__ out,
                               int R, int Cc) {
  __shared__ float tile[32][33];
  int c0 = blockIdx.x * 32, r0 = blockIdx.y * 32;
  int tx = threadIdx.x, ty = threadIdx.y;          // block (32,8)
  for (int i = 0; i < 32; i += 8)
    tile[ty + i][tx] = in[(size_t)(r0 + ty + i) * Cc + c0 + tx];
  __syncthreads();
  for (int i = 0; i < 32; i += 8)
    out[(size_t)(c0 + ty + i) * R + r0 + tx] = f2bf(tile[tx][ty + i]);
}

// -------- rel_table [2048][16] fp32 -> [16][2048] bf16, scaled by log2e ----
__global__ void transpose_table_k(const float* __restrict__ in, short* __restrict__ out) {
  int i = blockIdx.x * 256 + threadIdx.x;
  if (i >= 2048 * 16) return;
  int l = i >> 4, h = i & 15;
  out[h * 2048 + l] = f2bf(in[i] * 1.4426950408889634f);
}

// ---------------- mask [2][2048] int -> 64 u64 bitwords --------------------
__global__ void mask_pack(const int* __restrict__ mask, unsigned long long* __restrict__ mkb) {
  int g = blockIdx.x * 256 + threadIdx.x;          // 0..4095
  unsigned long long b = __ballot(mask[g] != 0);
  if ((threadIdx.x & 63) == 0) mkb[g >> 6] = b;
}

// ---------------- V pre-transpose: qkv V-part -> VT[n][vcol][s] bf16 -------
__global__ void vt_transpose(const short* __restrict__ qkv, short* __restrict__ vt) {
  __shared__ short tile[32][33];
  int nn = blockIdx.z;
  int c0 = blockIdx.y * 32;                        // v-col (= h*64+dd)
  int r0 = blockIdx.x * 32;                        // s
  int tx = threadIdx.x, ty = threadIdx.y;          // block (32,8)
  for (int i = 0; i < 32; i += 8)
    tile[ty + i][tx] = qkv[(size_t)(nn * 2048 + r0 + ty + i) * 3072 + 2048 + c0 + tx];
  __syncthreads();
  for (int i = 0; i < 32; i += 8)
    vt[(size_t)(nn * 1024 + c0 + ty + i) * 2048 + r0 + tx] = tile[tx][ty + i];
}

// ---------------- bf16 MFMA GEMM (m97 structure): C = A * BT^T -------------
template<bool OUT_F32>
__global__ __launch_bounds__(256) void gemm_bt(
    const short* __restrict__ A, const short* __restrict__ BT,
    void* __restrict__ Cout, int M, int Nn, int K)
{
  __shared__ short As[128 * 64];
  __shared__ short Bs[128 * 64];
  int bn = blockIdx.x, bm = blockIdx.y;
  int tid = threadIdx.x, wave = tid >> 6, lane = tid & 63;
  int wr = wave >> 1, wc = wave & 1;
  int lc = lane & 15, lg = lane >> 4;
  f32x4 acc[4][4];
  for (int i = 0; i < 4; ++i)
    for (int j = 0; j < 4; ++j) acc[i][j] = (f32x4){0.f, 0.f, 0.f, 0.f};
  const short* Abase = A  + (size_t)(bm * 128) * K;
  const short* Bbase = BT + (size_t)(bn * 128) * K;
  int srow = lane >> 3;
  int scol = (lane & 7) * 8;
  for (int k0 = 0; k0 < K; k0 += 64) {
    __syncthreads();
    #pragma unroll
    for (int it = 0; it < 4; ++it) {
      int chunk = it * 4 + wave;
      int grow = chunk * 8 + srow;
      gload_lds16(&Abase[(size_t)grow * K + k0 + scol], &As[chunk * 512]);
      gload_lds16(&Bbase[(size_t)grow * K + k0 + scol], &Bs[chunk * 512]);
    }
    __syncthreads();
    #pragma unroll
    for (int ks = 0; ks < 2; ++ks) {
      s16x8 af[4], bfr[4];
      #pragma unroll
      for (int mi = 0; mi < 4; ++mi)
        af[mi] = *(const s16x8*)&As[(wr * 64 + mi * 16 + lc) * 64 + ks * 32 + lg * 8];
      #pragma unroll
      for (int ni = 0; ni < 4; ++ni)
        bfr[ni] = *(const s16x8*)&Bs[(wc * 64 + ni * 16 + lc) * 64 + ks * 32 + lg * 8];
      #pragma unroll
      for (int mi = 0; mi < 4; ++mi)
        #pragma unroll
        for (int ni = 0; ni < 4; ++ni)
          acc[mi][ni] = __builtin_amdgcn_mfma_f32_16x16x32_bf16(af[mi], bfr[ni], acc[mi][ni], 0, 0, 0);
    }
  }
  int row0 = bm * 128 + wr * 64, col0 = bn * 128 + wc * 64;
  for (int mi = 0; mi < 4; ++mi)
    for (int ni = 0; ni < 4; ++ni)
      for (int r = 0; r < 4; ++r) {
        int row = row0 + mi * 16 + lg * 4 + r;
        int col = col0 + ni * 16 + lc;
        if constexpr (OUT_F32)
          ((float*)Cout)[(size_t)row * Nn + col] = acc[mi][ni][r];
        else
          ((short*)Cout)[(size_t)row * Nn + col] = f2bf(acc[mi][ni][r]);
      }
}

// ---------------- GEMM variant: 128x64 tile (for y = y_ws @ WoutT) ---------
__global__ __launch_bounds__(256) void gemm_bt64(
    const short* __restrict__ A, const short* __restrict__ BT,
    float* __restrict__ Cout, int M, int Nn, int K)
{
  __shared__ short As[128 * 64];
  __shared__ short Bs[64 * 64];
  int bn = blockIdx.x, bm = blockIdx.y;
  int tid = threadIdx.x, wave = tid >> 6, lane = tid & 63;
  int wr = wave >> 1, wc = wave & 1;
  int lc = lane & 15, lg = lane >> 4;
  f32x4 acc[4][2];
  for (int i = 0; i < 4; ++i)
    for (int j = 0; j < 2; ++j) acc[i][j] = (f32x4){0.f, 0.f, 0.f, 0.f};
  const short* Abase = A  + (size_t)(bm * 128) * K;
  const short* Bbase = BT + (size_t)(bn * 64) * K;
  int srow = lane >> 3;
  int scol = (lane & 7) * 8;
  for (int k0 = 0; k0 < K; k0 += 64) {
    __syncthreads();
    #pragma unroll
    for (int it = 0; it < 4; ++it) {
      int chunk = it * 4 + wave;
      gload_lds16(&Abase[(size_t)(chunk * 8 + srow) * K + k0 + scol], &As[chunk * 512]);
    }
    #pragma unroll
    for (int it = 0; it < 2; ++it) {
      int chunk = it * 4 + wave;
      gload_lds16(&Bbase[(size_t)(chunk * 8 + srow) * K + k0 + scol], &Bs[chunk * 512]);
    }
    __syncthreads();
    #pragma unroll
    for (int ks = 0; ks < 2; ++ks) {
      s16x8 af[4], bfr[2];
      #pragma unroll
      for (int mi = 0; mi < 4; ++mi)
        af[mi] = *(const s16x8*)&As[(wr * 64 + mi * 16 + lc) * 64 + ks * 32 + lg * 8];
      #pragma unroll
      for (int ni = 0; ni < 2; ++ni)
        bfr[ni] = *(const s16x8*)&Bs[(wc * 32 + ni * 16 + lc) * 64 + ks * 32 + lg * 8];
      #pragma unroll
      for (int mi = 0; mi < 4; ++mi)
        #pragma unroll
        for (int ni = 0; ni < 2; ++ni)
          acc[mi][ni] = __builtin_amdgcn_mfma_f32_16x16x32_bf16(af[mi], bfr[ni], acc[mi][ni], 0, 0, 0);
    }
  }
  int row0 = bm * 128 + wr * 64, col0 = bn * 64 + wc * 32;
  for (int mi = 0; mi < 4; ++mi)
    for (int ni = 0; ni < 2; ++ni)
      for (int r = 0; r < 4; ++r)
        Cout[(size_t)(row0 + mi * 16 + lg * 4 + r) * Nn + col0 + ni * 16 + lc] = acc[mi][ni][r];
}

// ---------------- fused attention: paired q-tiles, 8 waves, shared staging -
// grid 512 x 512 threads. Waves 0-3 own q-tile qa=qp, waves 4-7 own qb=31-qp;
// K/V staged ONCE per block for both tiles. Loop runs qb+1 iters; group A
// waves use idle iters (kt>qa) to write tile-A's upper-triangle zeros
// (overlapped with group B compute). Grid mapped so each CU's two resident
// blocks have qp + qp' = 15 -> constant 49 k-iters per CU (balance).
// Max-free log2-domain softmax (proven R5/R7); qv folded into C_.
// R4-proven inner loop: reg-prefetch dbuf, lgkm-only barriers (attn stores
// never drained), wave-local P strips (+fence, R7 lesson), btab LAST.
__global__ __launch_bounds__(512, 4) void attn_fused(
    const short* __restrict__ qkv,     // [4096][3072] bf16
    const short* __restrict__ vt,      // [2][1024][2048] bf16 (V^T)
    const unsigned long long* __restrict__ mkb,  // [2][32]
    const short* __restrict__ tabS,    // [16][2048] bf16, *log2e
    float* __restrict__ attn_out,      // [2][16][2048][2048]
    short* __restrict__ y_ws)          // [4096][1024] bf16
{
  int bid = blockIdx.x;
  int xcd = bid & 7;
  int j = bid >> 3;                    // 0..63
  int qp = j & 15;
  if (j & 32) qp = 15 - qp;            // 2nd residency slot: complementary qp
  int nh = xcd + 8 * (j >> 4);
  int n = nh >> 4, h = nh & 15;
  int qa = qp, qb = 31 - qp;

  int tid = threadIdx.x, wave = tid >> 6, lane = tid & 63;
  int grp = wave >> 2, w4 = wave & 3;
  int lc = lane & 15, lg = lane >> 4, lg4 = lg * 4;
  int qtm = grp ? qb : qa;             // my group's q-tile
  int grptid = tid & 255;

  __shared__ short QPs[2][64][72];     // Q then P, per group (wave-local strips)
  __shared__ short Ks[2][64][72];
  __shared__ short VTs[2][64][72];
  __shared__ short btab[2048];         // LAST: negative-index reads stay in LDS

  for (int i = tid; i < 2048; i += 512) btab[i] = tabS[h * 2048 + i];

  int sr = tid >> 3, sc = (tid & 7) * 8;           // 64-row staging: 1 vec/thread
  const short* kbase0 = qkv + (size_t)(n * 2048) * 3072 + 1024 + h * 64;
  const short* vtbase = vt + (size_t)(n * 1024 + h * 64) * 2048;
  const unsigned long long* mw = mkb + n * 32;
  float* aout = attn_out + (size_t)(n * 16 + h) * 2048 * 2048;

  // stage Q for both tiles (1024 chunks over 512 threads x2)
  #pragma unroll
  for (int it = 0; it < 2; ++it) {
    int lid = tid + it * 512;
    int t = lid >> 9, r = (lid >> 3) & 63, ck = (lid & 7) * 8;
    int qrowg = (t ? qb : qa) * 64 + r;
    *(s16x8*)&QPs[t][r][ck] =
        *(const s16x8*)&qkv[(size_t)(n * 2048 + qrowg) * 3072 + h * 64 + ck];
  }
  *(s16x8*)&Ks[0][sr][sc] = *(const s16x8*)&kbase0[(size_t)sr * 3072 + sc];
  __syncthreads();

  s16x8 aq[2];
  #pragma unroll
  for (int ks = 0; ks < 2; ++ks)
    aq[ks] = *(const s16x8*)&QPs[grp][w4 * 16 + lc][ks * 32 + lg * 8];
  int qrow = qtm * 64 + w4 * 16 + lc;
  bool qv = ((mw[qrow >> 6] >> (qrow & 63)) & 1ull) != 0;
  float l = 0.f;

  // ---------------- pass 1: row sums (max-free); A-idle = zero tiles -------
  for (int kt = 0; kt <= qb; ++kt) {
    int cur = kt & 1;
    s16x8 kn;
    if (kt < qb)
      kn = *(const s16x8*)&kbase0[(size_t)((kt + 1) * 64 + sr) * 3072 + sc];
    if (kt <= qtm) {
      unsigned long long w = mw[kt];
      int lim = qrow - kt * 64;
      f32x4 c[4];
      __builtin_amdgcn_s_setprio(1);
      #pragma unroll
      for (int ni = 0; ni < 4; ++ni) {
        c[ni] = (f32x4){0.f, 0.f, 0.f, 0.f};
        #pragma unroll
        for (int ks = 0; ks < 2; ++ks) {
          s16x8 kf = *(const s16x8*)&Ks[cur][ni * 16 + lc][ks * 32 + lg * 8];
          c[ni] = __builtin_amdgcn_mfma_f32_16x16x32_bf16(kf, aq[ks], c[ni], 0, 0, 0);
        }
      }
      __builtin_amdgcn_s_setprio(0);
      #pragma unroll
      for (int ni = 0; ni < 4; ++ni)
        #pragma unroll
        for (int r = 0; r < 4; ++r) {
          int idx = ni * 16 + lg4 + r;
          bool ok = (((w >> idx) & 1ull) != 0) && (idx <= lim);
          float bb = bf2f(btab[lim - idx]);        // OOB-neg garbage, masked
          float v = ok ? fmaf(c[ni][r], K1, bb) : NEGV;
          l += exp2f(v);
        }
    } else if (grp == 0) {
      // tile-A upper-triangle zeros for k-tile kt (overlaps B compute)
      float4 z4 = {0.f, 0.f, 0.f, 0.f};
      #pragma unroll
      for (int i = 0; i < 4; ++i) {
        int idx = grptid + i * 256;                // 0..1023
        int row = idx >> 4, c16 = idx & 15;
        *(float4*)&aout[(size_t)(qa * 64 + row) * 2048 + kt * 64 + c16 * 4] = z4;
      }
    }
    if (kt < qb)
      *(s16x8*)&Ks[cur ^ 1][sr][sc] = kn;
    block_sync_lds();
  }
  l += __shfl_xor(l, 16);
  l += __shfl_xor(l, 32);
  float C_ = qv ? __log2f(l) : 1.0e30f;  // invalid q-row: exp2(v-1e30) = 0

  f32x4 y[4];
  #pragma unroll
  for (int ni = 0; ni < 4; ++ni) y[ni] = (f32x4){0.f, 0.f, 0.f, 0.f};

  // re-stage tile 0 (K + VT) for pass 2
  *(s16x8*)&Ks[0][sr][sc]  = *(const s16x8*)&kbase0[(size_t)sr * 3072 + sc];
  *(s16x8*)&VTs[0][sr][sc] = *(const s16x8*)&vtbase[(size_t)sr * 2048 + sc];
  block_sync_lds();

  // ---------------- pass 2: normalized attn (float4) + PV ------------------
  for (int kt = 0; kt <= qb; ++kt) {
    int cur = kt & 1;
    s16x8 kn, vn;
    if (kt < qb) {
      kn = *(const s16x8*)&kbase0[(size_t)((kt + 1) * 64 + sr) * 3072 + sc];
      vn = *(const s16x8*)&vtbase[(size_t)sr * 2048 + (kt + 1) * 64 + sc];
    }
    if (kt <= qtm) {
      unsigned long long w = mw[kt];
      int lim = qrow - kt * 64;
      f32x4 c[4];
      __builtin_amdgcn_s_setprio(1);
      #pragma unroll
      for (int ni = 0; ni < 4; ++ni) {
        c[ni] = (f32x4){0.f, 0.f, 0.f, 0.f};
        #pragma unroll
        for (int ks = 0; ks < 2; ++ks) {
          s16x8 kf = *(const s16x8*)&Ks[cur][ni * 16 + lc][ks * 32 + lg * 8];
          c[ni] = __builtin_amdgcn_mfma_f32_16x16x32_bf16(kf, aq[ks], c[ni], 0, 0, 0);
        }
      }
      __builtin_amdgcn_s_setprio(0);
      #pragma unroll
      for (int ni = 0; ni < 4; ++ni) {
        float4 p4;
        #pragma unroll
        for (int r = 0; r < 4; ++r) {
          int idx = ni * 16 + lg4 + r;
          bool ok = (((w >> idx) & 1ull) != 0) && (idx <= lim);
          float bb = bf2f(btab[lim - idx]);
          float v = ok ? (fmaf(c[ni][r], K1, bb) - C_) : -3.0e38f;
          (&p4.x)[r] = exp2f(v);
        }
        *(float4*)&aout[(size_t)qrow * 2048 + kt * 64 + ni * 16 + lg4] = p4;
        unsigned plo = (unsigned)(unsigned short)f2bf(p4.x) | ((unsigned)(unsigned short)f2bf(p4.y) << 16);
        unsigned phi = (unsigned)(unsigned short)f2bf(p4.z) | ((unsigned)(unsigned short)f2bf(p4.w) << 16);
        uint2 pk; pk.x = plo; pk.y = phi;
        *(uint2*)&QPs[grp][w4 * 16 + lc][ni * 16 + lg4] = pk;  // wave-local strip
      }
      asm volatile("" ::: "memory");   // forbid hoisting P reads above writes
      __builtin_amdgcn_s_setprio(1);
      #pragma unroll
      for (int ks = 0; ks < 2; ++ks) {
        s16x8 pa = *(const s16x8*)&QPs[grp][w4 * 16 + lc][ks * 32 + lg * 8];
        #pragma unroll
        for (int ni = 0; ni < 4; ++ni) {
          s16x8 vfr = *(const s16x8*)&VTs[cur][ni * 16 + lc][ks * 32 + lg * 8];
          y[ni] = __builtin_amdgcn_mfma_f32_16x16x32_bf16(pa, vfr, y[ni], 0, 0, 0);
        }
      }
      __builtin_amdgcn_s_setprio(0);
    }
    if (kt < qb) {
      *(s16x8*)&Ks[cur ^ 1][sr][sc]  = kn;
      *(s16x8*)&VTs[cur ^ 1][sr][sc] = vn;
    }
    block_sync_lds();
  }

  // end-phase zeros: both groups zero their tile's cols >= (qb+1)*64
  {
    float4 z4 = {0.f, 0.f, 0.f, 0.f};
    for (int tz = 0; tz < qp; ++tz) {
      int ct = (qb + 1 + tz) * 64;
      #pragma unroll
      for (int i = 0; i < 4; ++i) {
        int idx = grptid + i * 256;
        int row = idx >> 4, c16 = idx & 15;
        *(float4*)&aout[(size_t)(qtm * 64 + row) * 2048 + ct + c16 * 4] = z4;
      }
    }
  }

  // y store (padded-query rows: p forced 0 -> y 0)
  #pragma unroll
  for (int ni = 0; ni < 4; ++ni) {
    int col = h * 64 + ni * 16 + lc;
    #pragma unroll
    for (int r = 0; r < 4; ++r) {
      size_t row = (size_t)(n * 2048 + qtm * 64 + w4 * 16 + lg4 + r);
      y_ws[row * 1024 + col] = f2bf(y[ni][r]);
    }
  }
}

// ---------------------------------------------------------------------------
extern "C" void kernel_launch(void* const* d_in, const int* in_sizes, int n_in,
                              void* d_out, int out_size, void* d_ws, size_t ws_size,
                              hipStream_t stream)
{
  const float* x         = (const float*)d_in[0];
  const int*   mask      = (const int*)d_in[1];
  const float* W_qkv     = (const float*)d_in[4];
  const float* W_out     = (const float*)d_in[5];
  const float* rel_table = (const float*)d_in[6];

  char* ws = (char*)d_ws;
  short*  xb     = (short*)(ws);                 //  8,388,608 B (reused as vt)
  short*  WqkvT  = (short*)(ws + 8388608);       //  6,291,456 B
  short*  WoutT  = (short*)(ws + 14680064);      //  2,097,152 B
  short*  tabS   = (short*)(ws + 16777216);      //     65,536 B
  unsigned long long* mkb = (unsigned long long*)(ws + 16842752); // 512 B
  short*  qkv    = (short*)(ws + 16908288);      // 25,165,824 B
  short*  y_ws   = (short*)(ws + 42074112);      //  8,388,608 B
  short*  vt     = xb;                           // V^T, written after gemm1 reads xb

  float* y_out    = (float*)d_out;
  float* attn_out = y_out + (size_t)2 * 2048 * 1024;

  cast_f32_bf16<<<2048, 256, 0, stream>>>(x, xb, 4194304);
  transpose_cast<<<dim3(3072 / 32, 1024 / 32), dim3(32, 8), 0, stream>>>(W_qkv, WqkvT, 1024, 3072);
  transpose_cast<<<dim3(1024 / 32, 1024 / 32), dim3(32, 8), 0, stream>>>(W_out, WoutT, 1024, 1024);
  transpose_table_k<<<128, 256, 0, stream>>>(rel_table, tabS);
  mask_pack<<<16, 256, 0, stream>>>(mask, mkb);

  gemm_bt<false><<<dim3(24, 32), 256, 0, stream>>>(xb, WqkvT, (void*)qkv, 4096, 3072, 1024);

  vt_transpose<<<dim3(64, 32, 2), dim3(32, 8), 0, stream>>>(qkv, vt);

  attn_fused<<<512, 512, 0, stream>>>(qkv, vt, mkb, tabS, attn_out, y_ws);

  gemm_bt64<<<dim3(16, 32), 256, 0, stream>>>(y_ws, WoutT, y_out, 4096, 1024, 1024);
}

// Round 9
// 290.963 us; speedup vs baseline: 1.4350x; 1.0146x over previous
//
#include <hip/hip_runtime.h>
#include <hip/hip_bf16.h>

// ---------------------------------------------------------------------------
// Problem: N=2, S=2048, C=1024, A=1024, H=16, d=64, MAXLEN=2048
// Outputs: y [2,2048,1024] fp32  then  attn [2,16,2048,2048] fp32 (concat flat)
// ---------------------------------------------------------------------------

typedef __attribute__((ext_vector_type(8))) short s16x8;   // 8 x bf16 bits (4 VGPR)
typedef __attribute__((ext_vector_type(4))) float f32x4;   // MFMA acc

#define NEGV (-1e30f)
#define K1   0.1803368801111244f   /* 0.125 * log2(e) */

static __device__ __forceinline__ short f2bf(float f) {
  unsigned u = __float_as_uint(f);
  unsigned r = (u + 0x7fffu + ((u >> 16) & 1u)) >> 16;
  return (short)r;
}

// async global->LDS, 16B per lane; lds dest wave-uniform (HW adds lane*16)
static __device__ __forceinline__ void gload_lds16(const void* g, void* l) {
  __builtin_amdgcn_global_load_lds(
      (const __attribute__((address_space(1))) void*)g,
      (__attribute__((address_space(3))) void*)l, 16, 0, 0);
}

// barrier that does NOT drain vmcnt: attn global stores stay in flight.
// staging is reg->ds_write, so lgkmcnt(0) suffices for LDS visibility.
static __device__ __forceinline__ void block_sync_lds() {
  __builtin_amdgcn_sched_barrier(0);
  asm volatile("s_waitcnt lgkmcnt(0)" ::: "memory");
  __builtin_amdgcn_s_barrier();
  __builtin_amdgcn_sched_barrier(0);
}

// ---------------- elementwise cast fp32 -> bf16 ----------------------------
__global__ void cast_f32_bf16(const float* __restrict__ in, short* __restrict__ out, int n) {
  int i = (blockIdx.x * 256 + threadIdx.x) * 8;
  if (i >= n) return;
  float4 a = *(const float4*)&in[i];
  float4 b = *(const float4*)&in[i + 4];
  s16x8 v;
  v[0] = f2bf(a.x); v[1] = f2bf(a.y); v[2] = f2bf(a.z); v[3] = f2bf(a.w);
  v[4] = f2bf(b.x); v[5] = f2bf(b.y); v[6] = f2bf(b.z); v[7] = f2bf(b.w);
  *(s16x8*)&out[i] = v;
}

// ---------------- transpose + cast: [R][Cc] fp32 -> [Cc][R] bf16 -----------
__global__ void transpose_cast(const float* __restrict__ in, short* __restrict__ out,
                               int R, int Cc) {
  __shared__ float tile[32][33];
  int c0 = blockIdx.x * 32, r0 = blockIdx.y * 32;
  int tx = threadIdx.x, ty = threadIdx.y;          // block (32,8)
  for (int i = 0; i < 32; i += 8)
    tile[ty + i][tx] = in[(size_t)(r0 + ty + i) * Cc + c0 + tx];
  __syncthreads();
  for (int i = 0; i < 32; i += 8)
    out[(size_t)(c0 + ty + i) * R + r0 + tx] = f2bf(tile[tx][ty + i]);
}

// -------- rel_table [2048][16] fp32 -> [16][2048] fp32, scaled by log2e ----
__global__ void transpose_table_k(const float* __restrict__ in, float* __restrict__ out) {
  int i = blockIdx.x * 256 + threadIdx.x;
  if (i >= 2048 * 16) return;
  int l = i >> 4, h = i & 15;
  out[h * 2048 + l] = in[i] * 1.4426950408889634f;
}

// ---------------- mask [2][2048] int -> 64 u64 bitwords --------------------
__global__ void mask_pack(const int* __restrict__ mask, unsigned long long* __restrict__ mkb) {
  int g = blockIdx.x * 256 + threadIdx.x;          // 0..4095
  unsigned long long b = __ballot(mask[g] != 0);
  if ((threadIdx.x & 63) == 0) mkb[g >> 6] = b;
}

// ---------------- V pre-transpose: qkv V-part -> VT[n][vcol][s] bf16 -------
__global__ void vt_transpose(const short* __restrict__ qkv, short* __restrict__ vt) {
  __shared__ short tile[32][33];
  int nn = blockIdx.z;
  int c0 = blockIdx.y * 32;                        // v-col (= h*64+dd)
  int r0 = blockIdx.x * 32;                        // s
  int tx = threadIdx.x, ty = threadIdx.y;          // block (32,8)
  for (int i = 0; i < 32; i += 8)
    tile[ty + i][tx] = qkv[(size_t)(nn * 2048 + r0 + ty + i) * 3072 + 2048 + c0 + tx];
  __syncthreads();
  for (int i = 0; i < 32; i += 8)
    vt[(size_t)(nn * 1024 + c0 + ty + i) * 2048 + r0 + tx] = tile[tx][ty + i];
}

// ---------------- bf16 MFMA GEMM (m97 structure): C = A * BT^T -------------
template<bool OUT_F32>
__global__ __launch_bounds__(256) void gemm_bt(
    const short* __restrict__ A, const short* __restrict__ BT,
    void* __restrict__ Cout, int M, int Nn, int K)
{
  __shared__ short As[128 * 64];
  __shared__ short Bs[128 * 64];
  int bn = blockIdx.x, bm = blockIdx.y;
  int tid = threadIdx.x, wave = tid >> 6, lane = tid & 63;
  int wr = wave >> 1, wc = wave & 1;
  int lc = lane & 15, lg = lane >> 4;
  f32x4 acc[4][4];
  for (int i = 0; i < 4; ++i)
    for (int j = 0; j < 4; ++j) acc[i][j] = (f32x4){0.f, 0.f, 0.f, 0.f};
  const short* Abase = A  + (size_t)(bm * 128) * K;
  const short* Bbase = BT + (size_t)(bn * 128) * K;
  int srow = lane >> 3;
  int scol = (lane & 7) * 8;
  for (int k0 = 0; k0 < K; k0 += 64) {
    __syncthreads();
    #pragma unroll
    for (int it = 0; it < 4; ++it) {
      int chunk = it * 4 + wave;
      int grow = chunk * 8 + srow;
      gload_lds16(&Abase[(size_t)grow * K + k0 + scol], &As[chunk * 512]);
      gload_lds16(&Bbase[(size_t)grow * K + k0 + scol], &Bs[chunk * 512]);
    }
    __syncthreads();
    #pragma unroll
    for (int ks = 0; ks < 2; ++ks) {
      s16x8 af[4], bfr[4];
      #pragma unroll
      for (int mi = 0; mi < 4; ++mi)
        af[mi] = *(const s16x8*)&As[(wr * 64 + mi * 16 + lc) * 64 + ks * 32 + lg * 8];
      #pragma unroll
      for (int ni = 0; ni < 4; ++ni)
        bfr[ni] = *(const s16x8*)&Bs[(wc * 64 + ni * 16 + lc) * 64 + ks * 32 + lg * 8];
      #pragma unroll
      for (int mi = 0; mi < 4; ++mi)
        #pragma unroll
        for (int ni = 0; ni < 4; ++ni)
          acc[mi][ni] = __builtin_amdgcn_mfma_f32_16x16x32_bf16(af[mi], bfr[ni], acc[mi][ni], 0, 0, 0);
    }
  }
  int row0 = bm * 128 + wr * 64, col0 = bn * 128 + wc * 64;
  for (int mi = 0; mi < 4; ++mi)
    for (int ni = 0; ni < 4; ++ni)
      for (int r = 0; r < 4; ++r) {
        int row = row0 + mi * 16 + lg * 4 + r;
        int col = col0 + ni * 16 + lc;
        if constexpr (OUT_F32)
          ((float*)Cout)[(size_t)row * Nn + col] = acc[mi][ni][r];
        else
          ((short*)Cout)[(size_t)row * Nn + col] = f2bf(acc[mi][ni][r]);
      }
}

// ---------------- GEMM variant: 128x64 tile (for y = y_ws @ WoutT) ---------
__global__ __launch_bounds__(256) void gemm_bt64(
    const short* __restrict__ A, const short* __restrict__ BT,
    float* __restrict__ Cout, int M, int Nn, int K)
{
  __shared__ short As[128 * 64];
  __shared__ short Bs[64 * 64];
  int bn = blockIdx.x, bm = blockIdx.y;
  int tid = threadIdx.x, wave = tid >> 6, lane = tid & 63;
  int wr = wave >> 1, wc = wave & 1;
  int lc = lane & 15, lg = lane >> 4;
  f32x4 acc[4][2];
  for (int i = 0; i < 4; ++i)
    for (int j = 0; j < 2; ++j) acc[i][j] = (f32x4){0.f, 0.f, 0.f, 0.f};
  const short* Abase = A  + (size_t)(bm * 128) * K;
  const short* Bbase = BT + (size_t)(bn * 64) * K;
  int srow = lane >> 3;
  int scol = (lane & 7) * 8;
  for (int k0 = 0; k0 < K; k0 += 64) {
    __syncthreads();
    #pragma unroll
    for (int it = 0; it < 4; ++it) {
      int chunk = it * 4 + wave;
      gload_lds16(&Abase[(size_t)(chunk * 8 + srow) * K + k0 + scol], &As[chunk * 512]);
    }
    #pragma unroll
    for (int it = 0; it < 2; ++it) {
      int chunk = it * 4 + wave;
      gload_lds16(&Bbase[(size_t)(chunk * 8 + srow) * K + k0 + scol], &Bs[chunk * 512]);
    }
    __syncthreads();
    #pragma unroll
    for (int ks = 0; ks < 2; ++ks) {
      s16x8 af[4], bfr[2];
      #pragma unroll
      for (int mi = 0; mi < 4; ++mi)
        af[mi] = *(const s16x8*)&As[(wr * 64 + mi * 16 + lc) * 64 + ks * 32 + lg * 8];
      #pragma unroll
      for (int ni = 0; ni < 2; ++ni)
        bfr[ni] = *(const s16x8*)&Bs[(wc * 32 + ni * 16 + lc) * 64 + ks * 32 + lg * 8];
      #pragma unroll
      for (int mi = 0; mi < 4; ++mi)
        #pragma unroll
        for (int ni = 0; ni < 2; ++ni)
          acc[mi][ni] = __builtin_amdgcn_mfma_f32_16x16x32_bf16(af[mi], bfr[ni], acc[mi][ni], 0, 0, 0);
    }
  }
  int row0 = bm * 128 + wr * 64, col0 = bn * 64 + wc * 32;
  for (int mi = 0; mi < 4; ++mi)
    for (int ni = 0; ni < 2; ++ni)
      for (int r = 0; r < 4; ++r)
        Cout[(size_t)(row0 + mi * 16 + lg * 4 + r) * Nn + col0 + ni * 16 + lc] = acc[mi][ni][r];
}

// ---------------- fused attention: paired q-tiles, 8 waves, shared staging -
// R8 skeleton + R9 deltas: reversed fp32 bias table (merged ds_read2 pairs,
// no bf2f), interior-tile fast path (no causal compare below diagonal),
// pass-1 4-slot K ring (VTs idle in pass 1) -> 1 barrier per 2 k-tiles,
// cheap RNA P-pack. Max-free log2-domain softmax; qv folded into C_.
__global__ __launch_bounds__(512, 4) void attn_fused(
    const short* __restrict__ qkv,     // [4096][3072] bf16
    const short* __restrict__ vt,      // [2][1024][2048] bf16 (V^T)
    const unsigned long long* __restrict__ mkb,  // [2][32]
    const float* __restrict__ tabF,    // [16][2048] fp32, *log2e
    float* __restrict__ attn_out,      // [2][16][2048][2048]
    short* __restrict__ y_ws)          // [4096][1024] bf16
{
  int bid = blockIdx.x;
  int xcd = bid & 7;
  int j = bid >> 3;                    // 0..63
  int qp = j & 15;
  if (j & 32) qp = 15 - qp;            // 2nd residency slot: complementary qp
  int nh = xcd + 8 * (j >> 4);
  int n = nh >> 4, h = nh & 15;
  int qa = qp, qb = 31 - qp;

  int tid = threadIdx.x, wave = tid >> 6, lane = tid & 63;
  int grp = wave >> 2, w4 = wave & 3;
  int lc = lane & 15, lg = lane >> 4, lg4 = lg * 4;
  int qtm = grp ? qb : qa;             // my group's q-tile
  int grptid = tid & 255;

  __shared__ short QPs[2][64][72];     // Q then P, per group (wave-local strips)
  __shared__ short Ks[2][64][72];
  __shared__ short VTs[2][64][72];     // pass 1: extra K ring slots; pass 2: V^T
  __shared__ float rtab[2048 + 64];    // reversed bias (fp32,*log2e); +64 OOB slack

  for (int i = tid; i < 2048; i += 512) rtab[2047 - i] = tabF[h * 2048 + i];

  int sr = tid >> 3, sc = (tid & 7) * 8;           // 64-row staging: 1 vec/thread
  const short* kbase0 = qkv + (size_t)(n * 2048) * 3072 + 1024 + h * 64;
  const short* vtbase = vt + (size_t)(n * 1024 + h * 64) * 2048;
  const unsigned long long* mw = mkb + n * 32;
  float* aout = attn_out + (size_t)(n * 16 + h) * 2048 * 2048;

  // stage Q for both tiles (1024 chunks over 512 threads x2)
  #pragma unroll
  for (int it = 0; it < 2; ++it) {
    int lid = tid + it * 512;
    int t = lid >> 9, r = (lid >> 3) & 63, ck = (lid & 7) * 8;
    int qrowg = (t ? qb : qa) * 64 + r;
    *(s16x8*)&QPs[t][r][ck] =
        *(const s16x8*)&qkv[(size_t)(n * 2048 + qrowg) * 3072 + h * 64 + ck];
  }
  // prologue: stage K tiles 0,1 into ring slots 0,1 (NT >= 17 always)
  *(s16x8*)&Ks[0][sr][sc] = *(const s16x8*)&kbase0[(size_t)sr * 3072 + sc];
  *(s16x8*)&Ks[1][sr][sc] = *(const s16x8*)&kbase0[(size_t)(64 + sr) * 3072 + sc];
  __syncthreads();

  s16x8 aq[2];
  #pragma unroll
  for (int ks = 0; ks < 2; ++ks)
    aq[ks] = *(const s16x8*)&QPs[grp][w4 * 16 + lc][ks * 32 + lg * 8];
  int qrow = qtm * 64 + w4 * 16 + lc;
  int qrow_min = qtm * 64 + w4 * 16;   // lane lc=0 in this wave's strip
  bool qv = ((mw[qrow >> 6] >> (qrow & 63)) & 1ull) != 0;
  float l = 0.f;
  int NT = qb + 1;                     // k-tiles staged per block

  // ---- pass-1 per-tile work (compute or tile-A zero-fill) ----
  auto p1_tile = [&](int kt, const short (*Kb)[72]) {
    if (kt <= qtm) {
      int lim = qrow - kt * 64;
      f32x4 c[4];
      __builtin_amdgcn_s_setprio(1);
      #pragma unroll
      for (int ni = 0; ni < 4; ++ni) {
        c[ni] = (f32x4){0.f, 0.f, 0.f, 0.f};
        #pragma unroll
        for (int ks = 0; ks < 2; ++ks) {
          s16x8 kf = *(const s16x8*)&Kb[ni * 16 + lc][ks * 32 + lg * 8];
          c[ni] = __builtin_amdgcn_mfma_f32_16x16x32_bf16(kf, aq[ks], c[ni], 0, 0, 0);
        }
      }
      __builtin_amdgcn_s_setprio(0);
      unsigned long long w = mw[kt];
      bool interior = (kt * 64 + 63) <= qrow_min;  // wave-uniform
      if (interior) {
        #pragma unroll
        for (int ni = 0; ni < 4; ++ni) {
          unsigned nib = (unsigned)(w >> (ni * 16 + lg4));
          int j0 = 2047 - lim + ni * 16 + lg4;
          #pragma unroll
          for (int r = 0; r < 4; ++r) {
            float v = ((nib >> r) & 1u) ? fmaf(c[ni][r], K1, rtab[j0 + r]) : NEGV;
            l += exp2f(v);
          }
        }
      } else {
        #pragma unroll
        for (int ni = 0; ni < 4; ++ni) {
          unsigned nib = (unsigned)(w >> (ni * 16 + lg4));
          int j0 = 2047 - lim + ni * 16 + lg4;
          #pragma unroll
          for (int r = 0; r < 4; ++r) {
            int idx = ni * 16 + lg4 + r;
            bool ok = (((nib >> r) & 1u) != 0) && (idx <= lim);
            float v = ok ? fmaf(c[ni][r], K1, rtab[j0 + r]) : NEGV;
            l += exp2f(v);
          }
        }
      }
    } else if (grp == 0) {             // tile-A upper-triangle zeros (overlaps B)
      float4 z4 = {0.f, 0.f, 0.f, 0.f};
      #pragma unroll
      for (int i = 0; i < 4; ++i) {
        int idx = grptid + i * 256;
        int row = idx >> 4, c16 = idx & 15;
        *(float4*)&aout[(size_t)(qa * 64 + row) * 2048 + kt * 64 + c16 * 4] = z4;
      }
    }
  };

  // ---- pass 1: 4-slot ring {Ks0,Ks1,VTs0,VTs1}, 1 barrier per 2 tiles ----
  for (int kt0 = 0; kt0 < NT; kt0 += 4) {
    {                                   // compute slots Ks0,Ks1; stage into VTs
      s16x8 ra, rb;
      bool ha = kt0 + 2 < NT, hb = kt0 + 3 < NT;
      if (ha) ra = *(const s16x8*)&kbase0[(size_t)((kt0 + 2) * 64 + sr) * 3072 + sc];
      if (hb) rb = *(const s16x8*)&kbase0[(size_t)((kt0 + 3) * 64 + sr) * 3072 + sc];
      p1_tile(kt0, Ks[0]);
      if (kt0 + 1 < NT) p1_tile(kt0 + 1, Ks[1]);
      if (ha) *(s16x8*)&VTs[0][sr][sc] = ra;
      if (hb) *(s16x8*)&VTs[1][sr][sc] = rb;
      block_sync_lds();
    }
    if (kt0 + 2 < NT) {                 // compute slots VTs0,VTs1; stage into Ks
      s16x8 ra, rb;
      bool ha = kt0 + 4 < NT, hb = kt0 + 5 < NT;
      if (ha) ra = *(const s16x8*)&kbase0[(size_t)((kt0 + 4) * 64 + sr) * 3072 + sc];
      if (hb) rb = *(const s16x8*)&kbase0[(size_t)((kt0 + 5) * 64 + sr) * 3072 + sc];
      p1_tile(kt0 + 2, VTs[0]);
      if (kt0 + 3 < NT) p1_tile(kt0 + 3, VTs[1]);
      if (ha) *(s16x8*)&Ks[0][sr][sc] = ra;
      if (hb) *(s16x8*)&Ks[1][sr][sc] = rb;
      block_sync_lds();
    }
  }
  l += __shfl_xor(l, 16);
  l += __shfl_xor(l, 32);
  float C_ = qv ? __log2f(l) : 1.0e30f;  // invalid q-row: exp2(v-1e30) = 0

  f32x4 y[4];
  #pragma unroll
  for (int ni = 0; ni < 4; ++ni) y[ni] = (f32x4){0.f, 0.f, 0.f, 0.f};

  // re-stage tile 0 (K + VT) for pass 2
  *(s16x8*)&Ks[0][sr][sc]  = *(const s16x8*)&kbase0[(size_t)sr * 3072 + sc];
  *(s16x8*)&VTs[0][sr][sc] = *(const s16x8*)&vtbase[(size_t)sr * 2048 + sc];
  block_sync_lds();

  // ---------------- pass 2: normalized attn (float4) + PV ------------------
  for (int kt = 0; kt < NT; ++kt) {
    int cur = kt & 1;
    s16x8 kn, vn;
    if (kt + 1 < NT) {
      kn = *(const s16x8*)&kbase0[(size_t)((kt + 1) * 64 + sr) * 3072 + sc];
      vn = *(const s16x8*)&vtbase[(size_t)sr * 2048 + (kt + 1) * 64 + sc];
    }
    if (kt <= qtm) {
      unsigned long long w = mw[kt];
      int lim = qrow - kt * 64;
      bool interior = (kt * 64 + 63) <= qrow_min;
      f32x4 c[4];
      __builtin_amdgcn_s_setprio(1);
      #pragma unroll
      for (int ni = 0; ni < 4; ++ni) {
        c[ni] = (f32x4){0.f, 0.f, 0.f, 0.f};
        #pragma unroll
        for (int ks = 0; ks < 2; ++ks) {
          s16x8 kf = *(const s16x8*)&Ks[cur][ni * 16 + lc][ks * 32 + lg * 8];
          c[ni] = __builtin_amdgcn_mfma_f32_16x16x32_bf16(kf, aq[ks], c[ni], 0, 0, 0);
        }
      }
      __builtin_amdgcn_s_setprio(0);
      #pragma unroll
      for (int ni = 0; ni < 4; ++ni) {
        unsigned nib = (unsigned)(w >> (ni * 16 + lg4));
        int j0 = 2047 - lim + ni * 16 + lg4;
        float4 p4;
        if (interior) {
          #pragma unroll
          for (int r = 0; r < 4; ++r) {
            float v = ((nib >> r) & 1u) ? (fmaf(c[ni][r], K1, rtab[j0 + r]) - C_) : -3.0e38f;
            (&p4.x)[r] = exp2f(v);
          }
        } else {
          #pragma unroll
          for (int r = 0; r < 4; ++r) {
            int idx = ni * 16 + lg4 + r;
            bool ok = (((nib >> r) & 1u) != 0) && (idx <= lim);
            float v = ok ? (fmaf(c[ni][r], K1, rtab[j0 + r]) - C_) : -3.0e38f;
            (&p4.x)[r] = exp2f(v);
          }
        }
        *(float4*)&aout[(size_t)qrow * 2048 + kt * 64 + ni * 16 + lg4] = p4;
        // cheap RNA bf16 pack (values in [0,1], ties negligible)
        unsigned plo = ((__float_as_uint(p4.x) + 0x8000u) >> 16) |
                       ((__float_as_uint(p4.y) + 0x8000u) & 0xffff0000u);
        unsigned phi = ((__float_as_uint(p4.z) + 0x8000u) >> 16) |
                       ((__float_as_uint(p4.w) + 0x8000u) & 0xffff0000u);
        uint2 pk; pk.x = plo; pk.y = phi;
        *(uint2*)&QPs[grp][w4 * 16 + lc][ni * 16 + lg4] = pk;  // wave-local strip
      }
      asm volatile("" ::: "memory");   // forbid hoisting P reads above writes
      __builtin_amdgcn_s_setprio(1);
      #pragma unroll
      for (int ks = 0; ks < 2; ++ks) {
        s16x8 pa = *(const s16x8*)&QPs[grp][w4 * 16 + lc][ks * 32 + lg * 8];
        #pragma unroll
        for (int ni = 0; ni < 4; ++ni) {
          s16x8 vfr = *(const s16x8*)&VTs[cur][ni * 16 + lc][ks * 32 + lg * 8];
          y[ni] = __builtin_amdgcn_mfma_f32_16x16x32_bf16(pa, vfr, y[ni], 0, 0, 0);
        }
      }
      __builtin_amdgcn_s_setprio(0);
    }
    if (kt + 1 < NT) {
      *(s16x8*)&Ks[cur ^ 1][sr][sc]  = kn;
      *(s16x8*)&VTs[cur ^ 1][sr][sc] = vn;
    }
    block_sync_lds();
  }

  // end-phase zeros: both groups zero their tile's cols >= (qb+1)*64
  {
    float4 z4 = {0.f, 0.f, 0.f, 0.f};
    for (int tz = 0; tz < qp; ++tz) {
      int ct = (qb + 1 + tz) * 64;
      #pragma unroll
      for (int i = 0; i < 4; ++i) {
        int idx = grptid + i * 256;
        int row = idx >> 4, c16 = idx & 15;
        *(float4*)&aout[(size_t)(qtm * 64 + row) * 2048 + ct + c16 * 4] = z4;
      }
    }
  }

  // y store (padded-query rows: p forced 0 -> y 0)
  #pragma unroll
  for (int ni = 0; ni < 4; ++ni) {
    int col = h * 64 + ni * 16 + lc;
    #pragma unroll
    for (int r = 0; r < 4; ++r) {
      size_t row = (size_t)(n * 2048 + qtm * 64 + w4 * 16 + lg4 + r);
      y_ws[row * 1024 + col] = f2bf(y[ni][r]);
    }
  }
}

// ---------------------------------------------------------------------------
extern "C" void kernel_launch(void* const* d_in, const int* in_sizes, int n_in,
                              void* d_out, int out_size, void* d_ws, size_t ws_size,
                              hipStream_t stream)
{
  const float* x         = (const float*)d_in[0];
  const int*   mask      = (const int*)d_in[1];
  const float* W_qkv     = (const float*)d_in[4];
  const float* W_out     = (const float*)d_in[5];
  const float* rel_table = (const float*)d_in[6];

  char* ws = (char*)d_ws;
  short*  xb     = (short*)(ws);                 //  8,388,608 B (reused as vt)
  short*  WqkvT  = (short*)(ws + 8388608);       //  6,291,456 B
  short*  WoutT  = (short*)(ws + 14680064);      //  2,097,152 B
  float*  tabF   = (float*)(ws + 16777216);      //    131,072 B
  unsigned long long* mkb = (unsigned long long*)(ws + 16908288); // 512 B
  short*  qkv    = (short*)(ws + 16908800);      // 25,165,824 B
  short*  y_ws   = (short*)(ws + 42074624);      //  8,388,608 B (ends 50,463,232)
  short*  vt     = xb;                           // V^T, written after gemm1 reads xb

  float* y_out    = (float*)d_out;
  float* attn_out = y_out + (size_t)2 * 2048 * 1024;

  cast_f32_bf16<<<2048, 256, 0, stream>>>(x, xb, 4194304);
  transpose_cast<<<dim3(3072 / 32, 1024 / 32), dim3(32, 8), 0, stream>>>(W_qkv, WqkvT, 1024, 3072);
  transpose_cast<<<dim3(1024 / 32, 1024 / 32), dim3(32, 8), 0, stream>>>(W_out, WoutT, 1024, 1024);
  transpose_table_k<<<128, 256, 0, stream>>>(rel_table, tabF);
  mask_pack<<<16, 256, 0, stream>>>(mask, mkb);

  gemm_bt<false><<<dim3(24, 32), 256, 0, stream>>>(xb, WqkvT, (void*)qkv, 4096, 3072, 1024);

  vt_transpose<<<dim3(64, 32, 2), dim3(32, 8), 0, stream>>>(qkv, vt);

  attn_fused<<<512, 512, 0, stream>>>(qkv, vt, mkb, tabF, attn_out, y_ws);

  gemm_bt64<<<dim3(16, 32), 256, 0, stream>>>(y_ws, WoutT, y_out, 4096, 1024, 1024);
}

// Round 10
// 285.620 us; speedup vs baseline: 1.4619x; 1.0187x over previous
//
#include <hip/hip_runtime.h>
#include <hip/hip_bf16.h>

// ---------------------------------------------------------------------------
// Problem: N=2, S=2048, C=1024, A=1024, H=16, d=64, MAXLEN=2048
// Outputs: y [2,2048,1024] fp32  then  attn [2,16,2048,2048] fp32 (concat flat)
// ---------------------------------------------------------------------------

typedef __attribute__((ext_vector_type(8))) short s16x8;   // 8 x bf16 bits (4 VGPR)
typedef __attribute__((ext_vector_type(4))) float f32x4;   // MFMA acc

#define NEGV (-1e30f)
#define K1   0.1803368801111244f   /* 0.125 * log2(e) */

static __device__ __forceinline__ short f2bf(float f) {
  unsigned u = __float_as_uint(f);
  unsigned r = (u + 0x7fffu + ((u >> 16) & 1u)) >> 16;
  return (short)r;
}

// async global->LDS, 16B per lane; lds dest wave-uniform (HW adds lane*16)
static __device__ __forceinline__ void gload_lds16(const void* g, void* l) {
  __builtin_amdgcn_global_load_lds(
      (const __attribute__((address_space(1))) void*)g,
      (__attribute__((address_space(3))) void*)l, 16, 0, 0);
}

// barrier that does NOT drain vmcnt: attn global stores stay in flight.
// staging is reg->ds_write, so lgkmcnt(0) suffices for LDS visibility.
static __device__ __forceinline__ void block_sync_lds() {
  __builtin_amdgcn_sched_barrier(0);
  asm volatile("s_waitcnt lgkmcnt(0)" ::: "memory");
  __builtin_amdgcn_s_barrier();
  __builtin_amdgcn_sched_barrier(0);
}

// ---------------- elementwise cast fp32 -> bf16 ----------------------------
__global__ void cast_f32_bf16(const float* __restrict__ in, short* __restrict__ out, int n) {
  int i = (blockIdx.x * 256 + threadIdx.x) * 8;
  if (i >= n) return;
  float4 a = *(const float4*)&in[i];
  float4 b = *(const float4*)&in[i + 4];
  s16x8 v;
  v[0] = f2bf(a.x); v[1] = f2bf(a.y); v[2] = f2bf(a.z); v[3] = f2bf(a.w);
  v[4] = f2bf(b.x); v[5] = f2bf(b.y); v[6] = f2bf(b.z); v[7] = f2bf(b.w);
  *(s16x8*)&out[i] = v;
}

// ---------------- transpose + cast: [R][Cc] fp32 -> [Cc][R] bf16 -----------
__global__ void transpose_cast(const float* __restrict__ in, short* __restrict__ out,
                               int R, int Cc) {
  __shared__ float tile[32][33];
  int c0 = blockIdx.x * 32, r0 = blockIdx.y * 32;
  int tx = threadIdx.x, ty = threadIdx.y;          // block (32,8)
  for (int i = 0; i < 32; i += 8)
    tile[ty + i][tx] = in[(size_t)(r0 + ty + i) * Cc + c0 + tx];
  __syncthreads();
  for (int i = 0; i < 32; i += 8)
    out[(size_t)(c0 + ty + i) * R + r0 + tx] = f2bf(tile[tx][ty + i]);
}

// -------- rel_table [2048][16] fp32 -> [16][2048] fp32, scaled by log2e ----
__global__ void transpose_table_k(const float* __restrict__ in, float* __restrict__ out) {
  int i = blockIdx.x * 256 + threadIdx.x;
  if (i >= 2048 * 16) return;
  int l = i >> 4, h = i & 15;
  out[h * 2048 + l] = in[i] * 1.4426950408889634f;
}

// ---------------- mask [2][2048] int -> 64 u64 bitwords --------------------
__global__ void mask_pack(const int* __restrict__ mask, unsigned long long* __restrict__ mkb) {
  int g = blockIdx.x * 256 + threadIdx.x;          // 0..4095
  unsigned long long b = __ballot(mask[g] != 0);
  if ((threadIdx.x & 63) == 0) mkb[g >> 6] = b;
}

// ---------------- V pre-transpose: qkv V-part -> VT[n][vcol][s] bf16 -------
__global__ void vt_transpose(const short* __restrict__ qkv, short* __restrict__ vt) {
  __shared__ short tile[32][33];
  int nn = blockIdx.z;
  int c0 = blockIdx.y * 32;                        // v-col (= h*64+dd)
  int r0 = blockIdx.x * 32;                        // s
  int tx = threadIdx.x, ty = threadIdx.y;          // block (32,8)
  for (int i = 0; i < 32; i += 8)
    tile[ty + i][tx] = qkv[(size_t)(nn * 2048 + r0 + ty + i) * 3072 + 2048 + c0 + tx];
  __syncthreads();
  for (int i = 0; i < 32; i += 8)
    vt[(size_t)(nn * 1024 + c0 + ty + i) * 2048 + r0 + tx] = tile[tx][ty + i];
}

// ---------------- bf16 MFMA GEMM (m97 structure): C = A * BT^T -------------
template<bool OUT_F32>
__global__ __launch_bounds__(256) void gemm_bt(
    const short* __restrict__ A, const short* __restrict__ BT,
    void* __restrict__ Cout, int M, int Nn, int K)
{
  __shared__ short As[128 * 64];
  __shared__ short Bs[128 * 64];
  int bn = blockIdx.x, bm = blockIdx.y;
  int tid = threadIdx.x, wave = tid >> 6, lane = tid & 63;
  int wr = wave >> 1, wc = wave & 1;
  int lc = lane & 15, lg = lane >> 4;
  f32x4 acc[4][4];
  for (int i = 0; i < 4; ++i)
    for (int j = 0; j < 4; ++j) acc[i][j] = (f32x4){0.f, 0.f, 0.f, 0.f};
  const short* Abase = A  + (size_t)(bm * 128) * K;
  const short* Bbase = BT + (size_t)(bn * 128) * K;
  int srow = lane >> 3;
  int scol = (lane & 7) * 8;
  for (int k0 = 0; k0 < K; k0 += 64) {
    __syncthreads();
    #pragma unroll
    for (int it = 0; it < 4; ++it) {
      int chunk = it * 4 + wave;
      int grow = chunk * 8 + srow;
      gload_lds16(&Abase[(size_t)grow * K + k0 + scol], &As[chunk * 512]);
      gload_lds16(&Bbase[(size_t)grow * K + k0 + scol], &Bs[chunk * 512]);
    }
    __syncthreads();
    #pragma unroll
    for (int ks = 0; ks < 2; ++ks) {
      s16x8 af[4], bfr[4];
      #pragma unroll
      for (int mi = 0; mi < 4; ++mi)
        af[mi] = *(const s16x8*)&As[(wr * 64 + mi * 16 + lc) * 64 + ks * 32 + lg * 8];
      #pragma unroll
      for (int ni = 0; ni < 4; ++ni)
        bfr[ni] = *(const s16x8*)&Bs[(wc * 64 + ni * 16 + lc) * 64 + ks * 32 + lg * 8];
      #pragma unroll
      for (int mi = 0; mi < 4; ++mi)
        #pragma unroll
        for (int ni = 0; ni < 4; ++ni)
          acc[mi][ni] = __builtin_amdgcn_mfma_f32_16x16x32_bf16(af[mi], bfr[ni], acc[mi][ni], 0, 0, 0);
    }
  }
  int row0 = bm * 128 + wr * 64, col0 = bn * 128 + wc * 64;
  for (int mi = 0; mi < 4; ++mi)
    for (int ni = 0; ni < 4; ++ni)
      for (int r = 0; r < 4; ++r) {
        int row = row0 + mi * 16 + lg * 4 + r;
        int col = col0 + ni * 16 + lc;
        if constexpr (OUT_F32)
          ((float*)Cout)[(size_t)row * Nn + col] = acc[mi][ni][r];
        else
          ((short*)Cout)[(size_t)row * Nn + col] = f2bf(acc[mi][ni][r]);
      }
}

// ---------------- GEMM variant: 128x64 tile (for y = y_ws @ WoutT) ---------
__global__ __launch_bounds__(256) void gemm_bt64(
    const short* __restrict__ A, const short* __restrict__ BT,
    float* __restrict__ Cout, int M, int Nn, int K)
{
  __shared__ short As[128 * 64];
  __shared__ short Bs[64 * 64];
  int bn = blockIdx.x, bm = blockIdx.y;
  int tid = threadIdx.x, wave = tid >> 6, lane = tid & 63;
  int wr = wave >> 1, wc = wave & 1;
  int lc = lane & 15, lg = lane >> 4;
  f32x4 acc[4][2];
  for (int i = 0; i < 4; ++i)
    for (int j = 0; j < 2; ++j) acc[i][j] = (f32x4){0.f, 0.f, 0.f, 0.f};
  const short* Abase = A  + (size_t)(bm * 128) * K;
  const short* Bbase = BT + (size_t)(bn * 64) * K;
  int srow = lane >> 3;
  int scol = (lane & 7) * 8;
  for (int k0 = 0; k0 < K; k0 += 64) {
    __syncthreads();
    #pragma unroll
    for (int it = 0; it < 4; ++it) {
      int chunk = it * 4 + wave;
      gload_lds16(&Abase[(size_t)(chunk * 8 + srow) * K + k0 + scol], &As[chunk * 512]);
    }
    #pragma unroll
    for (int it = 0; it < 2; ++it) {
      int chunk = it * 4 + wave;
      gload_lds16(&Bbase[(size_t)(chunk * 8 + srow) * K + k0 + scol], &Bs[chunk * 512]);
    }
    __syncthreads();
    #pragma unroll
    for (int ks = 0; ks < 2; ++ks) {
      s16x8 af[4], bfr[2];
      #pragma unroll
      for (int mi = 0; mi < 4; ++mi)
        af[mi] = *(const s16x8*)&As[(wr * 64 + mi * 16 + lc) * 64 + ks * 32 + lg * 8];
      #pragma unroll
      for (int ni = 0; ni < 2; ++ni)
        bfr[ni] = *(const s16x8*)&Bs[(wc * 32 + ni * 16 + lc) * 64 + ks * 32 + lg * 8];
      #pragma unroll
      for (int mi = 0; mi < 4; ++mi)
        #pragma unroll
        for (int ni = 0; ni < 2; ++ni)
          acc[mi][ni] = __builtin_amdgcn_mfma_f32_16x16x32_bf16(af[mi], bfr[ni], acc[mi][ni], 0, 0, 0);
    }
  }
  int row0 = bm * 128 + wr * 64, col0 = bn * 64 + wc * 32;
  for (int mi = 0; mi < 4; ++mi)
    for (int ni = 0; ni < 2; ++ni)
      for (int r = 0; r < 4; ++r)
        Cout[(size_t)(row0 + mi * 16 + lg * 4 + r) * Nn + col0 + ni * 16 + lc] = acc[mi][ni][r];
}

// ---------------- fused attention: 1024 fine blocks, zeros folded in pass 1
// grid 1024 x 256 (4 waves). bid -> slot=bid>>8, r=bid&255, nh=r&31 (bid%8 =
// nh%8 XCD affinity), i=r>>5. qt by slot: {i, 15-i, 16+i, 31-i} -> the 4
// blocks sharing a CU (bid, bid+256, ...) have qt sums = 62 (balance), and
// 4 independent blocks/CU drift in phase (store/compute interleave).
// Pass 1 = UNIFORM 32 rounds: kt<=qt computes row sums; kt>qt writes this
// q-tile's upper-triangle zeros (268MB of zeros now hidden under compute).
// Pass 2 = qt+1 rounds: emit normalized attn + PV, V read DIRECT from
// L2-resident VT (no V LDS staging). Max-free log2-domain softmax.
__global__ __launch_bounds__(256, 4) void attn_fused(
    const short* __restrict__ qkv,     // [4096][3072] bf16
    const short* __restrict__ vt,      // [2][1024][2048] bf16 (V^T)
    const unsigned long long* __restrict__ mkb,  // [2][32]
    const float* __restrict__ tabF,    // [16][2048] fp32, *log2e
    float* __restrict__ attn_out,      // [2][16][2048][2048]
    short* __restrict__ y_ws)          // [4096][1024] bf16
{
  int bid = blockIdx.x;
  int slot = bid >> 8, r_ = bid & 255;
  int nh = r_ & 31, i_ = r_ >> 5;
  int n = nh >> 4, h = nh & 15;
  int qt;                              // slot table: sums to 62 per (i_, nh)
  switch (slot) {
    case 0:  qt = i_;      break;      // 0..7
    case 1:  qt = 15 - i_; break;      // 15..8
    case 2:  qt = 16 + i_; break;      // 16..23
    default: qt = 31 - i_; break;      // 31..24
  }

  int tid = threadIdx.x, wave = tid >> 6, lane = tid & 63;
  int lc = lane & 15, lg = lane >> 4, lg4 = lg * 4;

  __shared__ short QPs[64][72];        // Q then P (wave-local 16-row strips)
  __shared__ short Ks[2][64][72];
  __shared__ float rtab[2048 + 64];    // reversed bias (fp32,*log2e); +64 slack

  for (int ii = tid; ii < 2048; ii += 256) rtab[2047 - ii] = tabF[h * 2048 + ii];

  int sr = tid >> 3, sc = (tid & 7) * 8;           // staging rows sr, sr+32
  const short* kbase0 = qkv + (size_t)(n * 2048) * 3072 + 1024 + h * 64;
  const short* vtbase = vt + (size_t)(n * 1024 + h * 64) * 2048;
  const unsigned long long* mw = mkb + n * 32;
  float* aout = attn_out + (size_t)(n * 16 + h) * 2048 * 2048;

  // stage Q + K0
  const short* qbase = qkv + (size_t)(n * 2048 + qt * 64) * 3072 + h * 64;
  *(s16x8*)&QPs[sr][sc]        = *(const s16x8*)&qbase[(size_t)sr * 3072 + sc];
  *(s16x8*)&QPs[sr + 32][sc]   = *(const s16x8*)&qbase[(size_t)(sr + 32) * 3072 + sc];
  *(s16x8*)&Ks[0][sr][sc]      = *(const s16x8*)&kbase0[(size_t)sr * 3072 + sc];
  *(s16x8*)&Ks[0][sr + 32][sc] = *(const s16x8*)&kbase0[(size_t)(sr + 32) * 3072 + sc];
  __syncthreads();

  s16x8 aq[2];
  #pragma unroll
  for (int ks = 0; ks < 2; ++ks)
    aq[ks] = *(const s16x8*)&QPs[wave * 16 + lc][ks * 32 + lg * 8];
  int qrow = qt * 64 + wave * 16 + lc;
  bool qv = ((mw[qrow >> 6] >> (qrow & 63)) & 1ull) != 0;
  float l = 0.f;

  // ---- pass 1: uniform 32 rounds (compute row sums OR zero-fill) ----------
  for (int kt = 0; kt < 32; ++kt) {
    int cur = kt & 1;
    s16x8 kn0, kn1;
    bool pf = (kt + 1 <= qt);
    if (pf) {
      const short* kb = kbase0 + (size_t)(kt + 1) * 64 * 3072;
      kn0 = *(const s16x8*)&kb[(size_t)sr * 3072 + sc];
      kn1 = *(const s16x8*)&kb[(size_t)(sr + 32) * 3072 + sc];
    }
    if (kt <= qt) {
      int lim = qrow - kt * 64;
      unsigned long long w = mw[kt];
      f32x4 c[4];
      __builtin_amdgcn_s_setprio(1);
      #pragma unroll
      for (int ni = 0; ni < 4; ++ni) {
        c[ni] = (f32x4){0.f, 0.f, 0.f, 0.f};
        #pragma unroll
        for (int ks = 0; ks < 2; ++ks) {
          s16x8 kf = *(const s16x8*)&Ks[cur][ni * 16 + lc][ks * 32 + lg * 8];
          c[ni] = __builtin_amdgcn_mfma_f32_16x16x32_bf16(kf, aq[ks], c[ni], 0, 0, 0);
        }
      }
      __builtin_amdgcn_s_setprio(0);
      if (kt < qt) {                   // interior: no causal compare needed
        #pragma unroll
        for (int ni = 0; ni < 4; ++ni) {
          unsigned nib = (unsigned)(w >> (ni * 16 + lg4));
          int j0 = 2047 - lim + ni * 16 + lg4;
          #pragma unroll
          for (int r = 0; r < 4; ++r) {
            float v = ((nib >> r) & 1u) ? fmaf(c[ni][r], K1, rtab[j0 + r]) : NEGV;
            l += exp2f(v);
          }
        }
      } else {                         // diagonal tile
        #pragma unroll
        for (int ni = 0; ni < 4; ++ni) {
          unsigned nib = (unsigned)(w >> (ni * 16 + lg4));
          int j0 = 2047 - lim + ni * 16 + lg4;
          #pragma unroll
          for (int r = 0; r < 4; ++r) {
            int idx = ni * 16 + lg4 + r;
            bool ok = (((nib >> r) & 1u) != 0) && (idx <= lim);
            float v = ok ? fmaf(c[ni][r], K1, rtab[j0 + r]) : NEGV;
            l += exp2f(v);
          }
        }
      }
    } else {
      // zero-fill this q-tile's k-tile kt (upper triangle), 256B/row bursts
      float4 z4 = {0.f, 0.f, 0.f, 0.f};
      #pragma unroll
      for (int ii = 0; ii < 4; ++ii) {
        int idx = tid + ii * 256;                  // 0..1023
        int row = idx >> 4, c16 = idx & 15;
        *(float4*)&aout[(size_t)(qt * 64 + row) * 2048 + kt * 64 + c16 * 4] = z4;
      }
    }
    if (pf) {
      *(s16x8*)&Ks[cur ^ 1][sr][sc]      = kn0;
      *(s16x8*)&Ks[cur ^ 1][sr + 32][sc] = kn1;
    }
    block_sync_lds();
  }
  l += __shfl_xor(l, 16);
  l += __shfl_xor(l, 32);
  float C_ = qv ? __log2f(l) : 1.0e30f;  // invalid q-row: exp2(v-1e30) = 0

  f32x4 y[4];
  #pragma unroll
  for (int ni = 0; ni < 4; ++ni) y[ni] = (f32x4){0.f, 0.f, 0.f, 0.f};

  // re-stage K0 for pass 2 (prev barrier protects)
  *(s16x8*)&Ks[0][sr][sc]      = *(const s16x8*)&kbase0[(size_t)sr * 3072 + sc];
  *(s16x8*)&Ks[0][sr + 32][sc] = *(const s16x8*)&kbase0[(size_t)(sr + 32) * 3072 + sc];
  block_sync_lds();

  // ---- pass 2: emit normalized attn (float4) + PV (V direct from L2) ------
  for (int kt = 0; kt <= qt; ++kt) {
    int cur = kt & 1;
    s16x8 kn0, kn1;
    if (kt < qt) {
      const short* kb = kbase0 + (size_t)(kt + 1) * 64 * 3072;
      kn0 = *(const s16x8*)&kb[(size_t)sr * 3072 + sc];
      kn1 = *(const s16x8*)&kb[(size_t)(sr + 32) * 3072 + sc];
    }
    // V frags direct from global (L2-resident); issued early, used post-emit
    const short* vp = vtbase + (size_t)lc * 2048 + kt * 64 + lg * 8;
    s16x8 vf[4][2];
    #pragma unroll
    for (int ni = 0; ni < 4; ++ni) {
      vf[ni][0] = *(const s16x8*)&vp[(size_t)(ni * 16) * 2048];
      vf[ni][1] = *(const s16x8*)&vp[(size_t)(ni * 16) * 2048 + 32];
    }
    unsigned long long w = mw[kt];
    int lim = qrow - kt * 64;
    f32x4 c[4];
    __builtin_amdgcn_s_setprio(1);
    #pragma unroll
    for (int ni = 0; ni < 4; ++ni) {
      c[ni] = (f32x4){0.f, 0.f, 0.f, 0.f};
      #pragma unroll
      for (int ks = 0; ks < 2; ++ks) {
        s16x8 kf = *(const s16x8*)&Ks[cur][ni * 16 + lc][ks * 32 + lg * 8];
        c[ni] = __builtin_amdgcn_mfma_f32_16x16x32_bf16(kf, aq[ks], c[ni], 0, 0, 0);
      }
    }
    __builtin_amdgcn_s_setprio(0);
    #pragma unroll
    for (int ni = 0; ni < 4; ++ni) {
      unsigned nib = (unsigned)(w >> (ni * 16 + lg4));
      int j0 = 2047 - lim + ni * 16 + lg4;
      float4 p4;
      if (kt < qt) {
        #pragma unroll
        for (int r = 0; r < 4; ++r) {
          float v = ((nib >> r) & 1u) ? (fmaf(c[ni][r], K1, rtab[j0 + r]) - C_) : -3.0e38f;
          (&p4.x)[r] = exp2f(v);
        }
      } else {
        #pragma unroll
        for (int r = 0; r < 4; ++r) {
          int idx = ni * 16 + lg4 + r;
          bool ok = (((nib >> r) & 1u) != 0) && (idx <= lim);
          float v = ok ? (fmaf(c[ni][r], K1, rtab[j0 + r]) - C_) : -3.0e38f;
          (&p4.x)[r] = exp2f(v);
        }
      }
      *(float4*)&aout[(size_t)qrow * 2048 + kt * 64 + ni * 16 + lg4] = p4;
      // cheap RNA bf16 pack (values in [0,1])
      unsigned plo = ((__float_as_uint(p4.x) + 0x8000u) >> 16) |
                     ((__float_as_uint(p4.y) + 0x8000u) & 0xffff0000u);
      unsigned phi = ((__float_as_uint(p4.z) + 0x8000u) >> 16) |
                     ((__float_as_uint(p4.w) + 0x8000u) & 0xffff0000u);
      uint2 pk; pk.x = plo; pk.y = phi;
      *(uint2*)&QPs[wave * 16 + lc][ni * 16 + lg4] = pk;  // wave-local strip
    }
    asm volatile("" ::: "memory");     // forbid hoisting P reads above writes
    __builtin_amdgcn_s_setprio(1);
    #pragma unroll
    for (int ks = 0; ks < 2; ++ks) {
      s16x8 pa = *(const s16x8*)&QPs[wave * 16 + lc][ks * 32 + lg * 8];
      #pragma unroll
      for (int ni = 0; ni < 4; ++ni)
        y[ni] = __builtin_amdgcn_mfma_f32_16x16x32_bf16(pa, vf[ni][ks], y[ni], 0, 0, 0);
    }
    __builtin_amdgcn_s_setprio(0);
    if (kt < qt) {
      *(s16x8*)&Ks[cur ^ 1][sr][sc]      = kn0;
      *(s16x8*)&Ks[cur ^ 1][sr + 32][sc] = kn1;
    }
    block_sync_lds();
  }

  // y store (padded-query rows: p forced 0 -> y 0)
  #pragma unroll
  for (int ni = 0; ni < 4; ++ni) {
    int col = h * 64 + ni * 16 + lc;
    #pragma unroll
    for (int r = 0; r < 4; ++r) {
      size_t row = (size_t)(n * 2048 + qt * 64 + wave * 16 + lg4 + r);
      y_ws[row * 1024 + col] = f2bf(y[ni][r]);
    }
  }
}

// ---------------------------------------------------------------------------
extern "C" void kernel_launch(void* const* d_in, const int* in_sizes, int n_in,
                              void* d_out, int out_size, void* d_ws, size_t ws_size,
                              hipStream_t stream)
{
  const float* x         = (const float*)d_in[0];
  const int*   mask      = (const int*)d_in[1];
  const float* W_qkv     = (const float*)d_in[4];
  const float* W_out     = (const float*)d_in[5];
  const float* rel_table = (const float*)d_in[6];

  char* ws = (char*)d_ws;
  short*  xb     = (short*)(ws);                 //  8,388,608 B (reused as vt)
  short*  WqkvT  = (short*)(ws + 8388608);       //  6,291,456 B
  short*  WoutT  = (short*)(ws + 14680064);      //  2,097,152 B
  float*  tabF   = (float*)(ws + 16777216);      //    131,072 B
  unsigned long long* mkb = (unsigned long long*)(ws + 16908288); // 512 B
  short*  qkv    = (short*)(ws + 16908800);      // 25,165,824 B
  short*  y_ws   = (short*)(ws + 42074624);      //  8,388,608 B (ends 50,463,232)
  short*  vt     = xb;                           // V^T, written after gemm1 reads xb

  float* y_out    = (float*)d_out;
  float* attn_out = y_out + (size_t)2 * 2048 * 1024;

  cast_f32_bf16<<<2048, 256, 0, stream>>>(x, xb, 4194304);
  transpose_cast<<<dim3(3072 / 32, 1024 / 32), dim3(32, 8), 0, stream>>>(W_qkv, WqkvT, 1024, 3072);
  transpose_cast<<<dim3(1024 / 32, 1024 / 32), dim3(32, 8), 0, stream>>>(W_out, WoutT, 1024, 1024);
  transpose_table_k<<<128, 256, 0, stream>>>(rel_table, tabF);
  mask_pack<<<16, 256, 0, stream>>>(mask, mkb);

  gemm_bt<false><<<dim3(24, 32), 256, 0, stream>>>(xb, WqkvT, (void*)qkv, 4096, 3072, 1024);

  vt_transpose<<<dim3(64, 32, 2), dim3(32, 8), 0, stream>>>(qkv, vt);

  attn_fused<<<1024, 256, 0, stream>>>(qkv, vt, mkb, tabF, attn_out, y_ws);

  gemm_bt64<<<dim3(16, 32), 256, 0, stream>>>(y_ws, WoutT, y_out, 4096, 1024, 1024);
}